// Round 2
// baseline (265.539 us; speedup 1.0000x reference)
//
#include <hip/hip_runtime.h>

// LinearCRF: mean_b( logZ_b - gold_b ), B=8192, L=1024, S=3.
// Scaled linear-domain forward: lane owns a 16-step chunk, builds the 3x3
// transfer-matrix product in linear space with exact power-of-2 renorm;
// 6-stage ordered shfl_xor butterfly composes 64 chunks per wave
// (1 wave = 1 sequence). Gold score fused.
// R5: ROLLED LOOPS. R2/R3/R4 (AoS burst / grouped / coalesced+LDS) all
// measured 65-70us with identical VALUBusy 27% -- bottleneck is invariant
// to data-access structure. The shared trait: ~25KB of fully-unrolled
// straight-line code => zero I$ reuse per wave, continuous front-end
// misses throttle issue. Main loop rolled to 4 iterations (4 steps + one
// 5-load group each, register indices still static); butterfly rolled to
// 6 iterations with gold reduce fused. I-footprint ~2KB => I$-resident.
// launch_bounds(256,8): VGPR<=64 keeps HW cap at 8 waves/SIMD.
// LDS: 9-word trans LUT (conflict-free: words hit distinct banks) + red[].

#define LOG2E 1.4426950408889634f
#define LN2   0.6931471805599453f

constexpr int B = 8192;
constexpr int L = 1024;
constexpr int SEQS_PER_BLOCK = 4;   // 4 waves of 64 per block

__device__ __forceinline__ float fexp2(float x) { return __builtin_amdgcn_exp2f(x); }
__device__ __forceinline__ float flog2(float x) { return __builtin_amdgcn_logf(x); }

__device__ __forceinline__ float f4get(const float4& v, int c) {
  return c == 0 ? v.x : (c == 1 ? v.y : (c == 2 ? v.z : v.w));
}

__device__ __forceinline__ float mux3(float x0, float x1, float x2, int i) {
  return (i == 0) ? x0 : ((i == 1) ? x1 : x2);
}

// Exact power-of-2 renormalization: P *= 2^-ex, scale += ex.
__device__ __forceinline__ void renorm3(float* __restrict__ P, float& scale) {
  float m = P[0];
  #pragma unroll
  for (int e = 1; e < 9; ++e) m = fmaxf(m, P[e]);
  int ex;
  (void)frexpf(m, &ex);
  #pragma unroll
  for (int e = 0; e < 9; ++e) P[e] = ldexpf(P[e], -ex);
  scale += (float)ex;
}

__global__ __launch_bounds__(256, 8) void crf_main(
    const float* __restrict__ em, const float* __restrict__ mask,
    const float* __restrict__ trans, const int* __restrict__ tags,
    float* __restrict__ out) {
  const int lane = threadIdx.x & 63;
  const int wid = threadIdx.x >> 6;
  const int b = blockIdx.x * SEQS_PER_BLOCK + wid;

  __shared__ float sT2[12];            // 9 used: trans * log2(e)
  __shared__ float red[SEQS_PER_BLOCK];
  if (threadIdx.x < 9) sT2[threadIdx.x] = trans[threadIdx.x] * LOG2E;
  __syncthreads();

  // Per-lane chunk pointers (AoS: lane owns steps 16*lane..16*lane+15).
  const float4* emp = (const float4*)(em + (size_t)b * (L * 3)) + lane * 12;
  const float4* mkp = (const float4*)(mask + (size_t)b * L) + lane * 4;
  const int4*   tgp = (const int4*)(tags + (size_t)b * L) + lane * 4;

  // Transitions in linear form (uniform -> scalar loads + 9 exp2).
  float tk[9];
  #pragma unroll
  for (int e = 0; e < 9; ++e) tk[e] = fexp2(trans[e] * LOG2E);

  float P[9] = {1.f, 0.f, 0.f, 0.f, 1.f, 0.f, 0.f, 0.f, 1.f};
  float scale = 0.f, gold = 0.f;
  float a0 = 0.f, a1 = 0.f, a2 = 0.f;   // chunk-step-0 linear emissions
  float e0_sel = 0.f, mk0 = 0.f;        // deferred chunk-step-0 gold term
  int tag0 = 0, prev = 0;

  // ---- rolled main loop: 4 groups x 4 steps; loads stay per-group ----
  #pragma unroll 1
  for (int g = 0; g < 4; ++g) {
    const float4 E0 = emp[3 * g + 0];
    const float4 E1 = emp[3 * g + 1];
    const float4 E2 = emp[3 * g + 2];
    const float4 MKg = mkp[g];
    const int4 tg = tgp[g];
    const int tp = tg.x | (tg.y << 2) | (tg.z << 4) | (tg.w << 6);
    const float ev[12] = {E0.x, E0.y, E0.z, E0.w, E1.x, E1.y,
                          E1.z, E1.w, E2.x, E2.y, E2.z, E2.w};

    #pragma unroll
    for (int q = 0; q < 4; ++q) {
      const float ev0 = ev[3 * q + 0] * LOG2E;
      const float ev1 = ev[3 * q + 1] * LOG2E;
      const float ev2 = ev[3 * q + 2] * LOG2E;
      const float m   = f4get(MKg, q);
      const int   cur = (tp >> (2 * q)) & 3;

      // ---- gold score (log2 domain); trans score via LDS LUT ----
      const float e = mux3(ev0, ev1, ev2, cur);
      if (q == 0) {
        if (g == 0) { e0_sel = e; mk0 = m; tag0 = cur; }  // deferred
        else        gold = fmaf(sT2[3 * prev + cur] + e, m, gold);
      } else {
        gold = fmaf(sT2[3 * prev + cur] + e, m, gold);
      }
      prev = cur;

      // ---- matrix step (linear domain): M = act ? tk.*w : I ----
      const float w0 = fexp2(ev0);
      const float w1 = fexp2(ev1);
      const float w2 = fexp2(ev2);
      if (q == 0 && g == 0) { a0 = w0; a1 = w1; a2 = w2; }
      const bool first = (q == 0) && (g == 0);
      const bool act = (m > 0.f) && !(first && lane == 0);  // t=0 is alpha0
      const float gg = act ? 1.f : 0.f;
      const float c1 = 1.f - gg;
      const float u0 = w0 * gg, u1 = w1 * gg, u2 = w2 * gg;
      float M[9];
      M[0] = fmaf(tk[0], u0, c1); M[1] = tk[1] * u1;           M[2] = tk[2] * u2;
      M[3] = tk[3] * u0;          M[4] = fmaf(tk[4], u1, c1);  M[5] = tk[5] * u2;
      M[6] = tk[6] * u0;          M[7] = tk[7] * u1;           M[8] = fmaf(tk[8], u2, c1);
      // in-place P <- P*M (row i of result depends only on row i of P)
      #pragma unroll
      for (int i = 0; i < 3; ++i) {
        const float p0 = P[3 * i + 0], p1 = P[3 * i + 1], p2 = P[3 * i + 2];
        P[3 * i + 0] = p0 * M[0] + p1 * M[3] + p2 * M[6];
        P[3 * i + 1] = p0 * M[1] + p1 * M[4] + p2 * M[7];
        P[3 * i + 2] = p0 * M[2] + p1 * M[5] + p2 * M[8];
      }
    }
    if (g & 1) renorm3(P, scale);  // after s==7 and s==15: bound fp32 range
  }

  // ---- deferred chunk-step-0 gold term (needs previous lane's last tag) ----
  const int prevLast = __shfl_up(prev, 1);     // prev == tag15 here
  const float t0 = sT2[3 * prevLast + tag0];
  gold = fmaf((lane == 0 ? 0.f : t0) + e0_sel, mk0, gold);

  // ---- rolled ordered butterfly combine + fused gold reduce ----
  // (entries <= 3^6 = 729 growth per stage chain: no renorm needed)
  #pragma unroll 1
  for (int d = 1; d < 64; d <<= 1) {
    float o[9];
    #pragma unroll
    for (int e = 0; e < 9; ++e) o[e] = __shfl_xor(P[e], d, 64);
    const float osc = __shfl_xor(scale, d, 64);
    gold += __shfl_xor(gold, d, 64);
    const bool later = (lane & d) != 0;  // self covers the later time segment
    float A[9], Bm[9];
    #pragma unroll
    for (int e = 0; e < 9; ++e) {
      A[e]  = later ? o[e] : P[e];
      Bm[e] = later ? P[e] : o[e];
    }
    #pragma unroll
    for (int i = 0; i < 3; ++i) {
      const float p0 = A[3 * i + 0], p1 = A[3 * i + 1], p2 = A[3 * i + 2];
      P[3 * i + 0] = p0 * Bm[0] + p1 * Bm[3] + p2 * Bm[6];
      P[3 * i + 1] = p0 * Bm[1] + p1 * Bm[4] + p2 * Bm[7];
      P[3 * i + 2] = p0 * Bm[2] + p1 * Bm[5] + p2 * Bm[8];
    }
    scale += osc;
  }

  // ---- finalize + block reduce + atomic ----
  if (lane == 0) {
    const float z = a0 * (P[0] + P[1] + P[2]) +
                    a1 * (P[3] + P[4] + P[5]) +
                    a2 * (P[6] + P[7] + P[8]);
    red[wid] = LN2 * (scale + flog2(z) - gold);
  }
  __syncthreads();
  if (threadIdx.x == 0) {
    const float s = red[0] + red[1] + red[2] + red[3];
    atomicAdd(out, s * (1.0f / (float)B));
  }
}

extern "C" void kernel_launch(void* const* d_in, const int* in_sizes, int n_in,
                              void* d_out, int out_size, void* d_ws, size_t ws_size,
                              hipStream_t stream) {
  const float* em    = (const float*)d_in[0];
  const float* mask  = (const float*)d_in[1];
  const float* trans = (const float*)d_in[2];
  const int*   tags  = (const int*)d_in[3];
  float* out = (float*)d_out;

  hipMemsetAsync(out, 0, sizeof(float), stream);  // atomic accumulator init
  crf_main<<<B / SEQS_PER_BLOCK, 256, 0, stream>>>(em, mask, trans, tags, out);
}

// Round 3
// 220.413 us; speedup vs baseline: 1.2047x; 1.2047x over previous
//
#include <hip/hip_runtime.h>

// LinearCRF: mean_b( logZ_b - gold_b ), B=8192, L=1024, S=3.
// Scaled linear-domain forward: lane owns a 16-step chunk, builds the 3x3
// transfer-matrix product in linear space with exact power-of-2 renorm;
// 6-stage ordered shfl_xor butterfly composes 64 chunks per wave
// (1 wave = 1 sequence). Gold score fused.
// R6: R5's rolled loops (I-footprint ~2KB, testing the I$-thrash theory
// for the 65us/VALUBusy-27% plateau of R2-R4) but WITHOUT R5's fatal
// launch_bounds(256,8): that capped VGPR at 32 and spilled all state to
// scratch (WRITE_SIZE 64KB->86MB, FETCH 82->372MB, dur 134us). R5 did
// prove the memory system delivers 3.5TB/s at 74% occupancy -- the 65us
// plateau was never a BW wall. launch_bounds(256,4) restores the 128-VGPR
// budget (R3/R4 compiled to ~60-64, zero spill). ev[] array replaced by
// static float4-component muxing (defense vs rule-#20 scratch alloc).

#define LOG2E 1.4426950408889634f
#define LN2   0.6931471805599453f

constexpr int B = 8192;
constexpr int L = 1024;
constexpr int SEQS_PER_BLOCK = 4;   // 4 waves of 64 per block

__device__ __forceinline__ float fexp2(float x) { return __builtin_amdgcn_exp2f(x); }
__device__ __forceinline__ float flog2(float x) { return __builtin_amdgcn_logf(x); }

__device__ __forceinline__ float f4get(const float4& v, int c) {
  return c == 0 ? v.x : (c == 1 ? v.y : (c == 2 ? v.z : v.w));
}

__device__ __forceinline__ float mux3(float x0, float x1, float x2, int i) {
  return (i == 0) ? x0 : ((i == 1) ? x1 : x2);
}

// Exact power-of-2 renormalization: P *= 2^-ex, scale += ex.
__device__ __forceinline__ void renorm3(float* __restrict__ P, float& scale) {
  float m = P[0];
  #pragma unroll
  for (int e = 1; e < 9; ++e) m = fmaxf(m, P[e]);
  int ex;
  (void)frexpf(m, &ex);
  #pragma unroll
  for (int e = 0; e < 9; ++e) P[e] = ldexpf(P[e], -ex);
  scale += (float)ex;
}

__global__ __launch_bounds__(256, 4) void crf_main(
    const float* __restrict__ em, const float* __restrict__ mask,
    const float* __restrict__ trans, const int* __restrict__ tags,
    float* __restrict__ out) {
  const int lane = threadIdx.x & 63;
  const int wid = threadIdx.x >> 6;
  const int b = blockIdx.x * SEQS_PER_BLOCK + wid;

  __shared__ float sT2[12];            // 9 used: trans * log2(e)
  __shared__ float red[SEQS_PER_BLOCK];
  if (threadIdx.x < 9) sT2[threadIdx.x] = trans[threadIdx.x] * LOG2E;
  __syncthreads();

  // Per-lane chunk pointers (AoS: lane owns steps 16*lane..16*lane+15).
  const float4* emp = (const float4*)(em + (size_t)b * (L * 3)) + lane * 12;
  const float4* mkp = (const float4*)(mask + (size_t)b * L) + lane * 4;
  const int4*   tgp = (const int4*)(tags + (size_t)b * L) + lane * 4;

  // Transitions in linear form (uniform -> scalar loads + 9 exp2).
  float tk[9];
  #pragma unroll
  for (int e = 0; e < 9; ++e) tk[e] = fexp2(trans[e] * LOG2E);

  float P[9] = {1.f, 0.f, 0.f, 0.f, 1.f, 0.f, 0.f, 0.f, 1.f};
  float scale = 0.f, gold = 0.f;
  float a0 = 0.f, a1 = 0.f, a2 = 0.f;   // chunk-step-0 linear emissions
  float e0_sel = 0.f, mk0 = 0.f;        // deferred chunk-step-0 gold term
  int tag0 = 0, prev = 0;

  // ---- rolled main loop: 4 groups x 4 steps; loads stay per-group ----
  #pragma unroll 1
  for (int g = 0; g < 4; ++g) {
    const float4 E0 = emp[3 * g + 0];
    const float4 E1 = emp[3 * g + 1];
    const float4 E2 = emp[3 * g + 2];
    const float4 MKg = mkp[g];
    const int4 tg = tgp[g];
    const int tp = tg.x | (tg.y << 2) | (tg.z << 4) | (tg.w << 6);

    #pragma unroll
    for (int q = 0; q < 4; ++q) {
      // static element->register muxing (q is compile-time after unroll)
      const int i0 = 3 * q + 0, i1 = 3 * q + 1, i2 = 3 * q + 2;
      const float ev0 = f4get(i0 < 4 ? E0 : (i0 < 8 ? E1 : E2), i0 & 3) * LOG2E;
      const float ev1 = f4get(i1 < 4 ? E0 : (i1 < 8 ? E1 : E2), i1 & 3) * LOG2E;
      const float ev2 = f4get(i2 < 4 ? E0 : (i2 < 8 ? E1 : E2), i2 & 3) * LOG2E;
      const float m   = f4get(MKg, q);
      const int   cur = (tp >> (2 * q)) & 3;

      // ---- gold score (log2 domain); trans score via LDS LUT ----
      const float e = mux3(ev0, ev1, ev2, cur);
      if (q == 0 && g == 0) {
        e0_sel = e; mk0 = m; tag0 = cur;   // deferred: needs prev lane's tag
      } else {
        gold = fmaf(sT2[3 * prev + cur] + e, m, gold);
      }
      prev = cur;

      // ---- matrix step (linear domain): M = act ? tk.*w : I ----
      const float w0 = fexp2(ev0);
      const float w1 = fexp2(ev1);
      const float w2 = fexp2(ev2);
      if (q == 0 && g == 0) { a0 = w0; a1 = w1; a2 = w2; }
      const bool first = (q == 0) && (g == 0);
      const bool act = (m > 0.f) && !(first && lane == 0);  // t=0 is alpha0
      const float gg = act ? 1.f : 0.f;
      const float c1 = 1.f - gg;
      const float u0 = w0 * gg, u1 = w1 * gg, u2 = w2 * gg;
      float M[9];
      M[0] = fmaf(tk[0], u0, c1); M[1] = tk[1] * u1;           M[2] = tk[2] * u2;
      M[3] = tk[3] * u0;          M[4] = fmaf(tk[4], u1, c1);  M[5] = tk[5] * u2;
      M[6] = tk[6] * u0;          M[7] = tk[7] * u1;           M[8] = fmaf(tk[8], u2, c1);
      // in-place P <- P*M (row i of result depends only on row i of P)
      #pragma unroll
      for (int i = 0; i < 3; ++i) {
        const float p0 = P[3 * i + 0], p1 = P[3 * i + 1], p2 = P[3 * i + 2];
        P[3 * i + 0] = p0 * M[0] + p1 * M[3] + p2 * M[6];
        P[3 * i + 1] = p0 * M[1] + p1 * M[4] + p2 * M[7];
        P[3 * i + 2] = p0 * M[2] + p1 * M[5] + p2 * M[8];
      }
    }
    if (g & 1) renorm3(P, scale);  // after s==7 and s==15: bound fp32 range
  }

  // ---- deferred chunk-step-0 gold term (needs previous lane's last tag) ----
  const int prevLast = __shfl_up(prev, 1);     // prev == tag15 here
  const float t0 = sT2[3 * prevLast + tag0];
  gold = fmaf((lane == 0 ? 0.f : t0) + e0_sel, mk0, gold);

  // ---- rolled ordered butterfly combine + fused gold reduce ----
  // (entries <= 3^6 = 729 growth per stage chain: no renorm needed)
  #pragma unroll 1
  for (int d = 1; d < 64; d <<= 1) {
    float o[9];
    #pragma unroll
    for (int e = 0; e < 9; ++e) o[e] = __shfl_xor(P[e], d, 64);
    const float osc = __shfl_xor(scale, d, 64);
    gold += __shfl_xor(gold, d, 64);
    const bool later = (lane & d) != 0;  // self covers the later time segment
    float A[9], Bm[9];
    #pragma unroll
    for (int e = 0; e < 9; ++e) {
      A[e]  = later ? o[e] : P[e];
      Bm[e] = later ? P[e] : o[e];
    }
    #pragma unroll
    for (int i = 0; i < 3; ++i) {
      const float p0 = A[3 * i + 0], p1 = A[3 * i + 1], p2 = A[3 * i + 2];
      P[3 * i + 0] = p0 * Bm[0] + p1 * Bm[3] + p2 * Bm[6];
      P[3 * i + 1] = p0 * Bm[1] + p1 * Bm[4] + p2 * Bm[7];
      P[3 * i + 2] = p0 * Bm[2] + p1 * Bm[5] + p2 * Bm[8];
    }
    scale += osc;
  }

  // ---- finalize + block reduce + atomic ----
  if (lane == 0) {
    const float z = a0 * (P[0] + P[1] + P[2]) +
                    a1 * (P[3] + P[4] + P[5]) +
                    a2 * (P[6] + P[7] + P[8]);
    red[wid] = LN2 * (scale + flog2(z) - gold);
  }
  __syncthreads();
  if (threadIdx.x == 0) {
    const float s = red[0] + red[1] + red[2] + red[3];
    atomicAdd(out, s * (1.0f / (float)B));
  }
}

extern "C" void kernel_launch(void* const* d_in, const int* in_sizes, int n_in,
                              void* d_out, int out_size, void* d_ws, size_t ws_size,
                              hipStream_t stream) {
  const float* em    = (const float*)d_in[0];
  const float* mask  = (const float*)d_in[1];
  const float* trans = (const float*)d_in[2];
  const int*   tags  = (const int*)d_in[3];
  float* out = (float*)d_out;

  hipMemsetAsync(out, 0, sizeof(float), stream);  // atomic accumulator init
  crf_main<<<B / SEQS_PER_BLOCK, 256, 0, stream>>>(em, mask, trans, tags, out);
}

// Round 5
// 194.796 us; speedup vs baseline: 1.3632x; 1.1315x over previous
//
#include <hip/hip_runtime.h>

// LinearCRF: mean_b( logZ_b - gold_b ), B=8192, L=1024, S=3.
// Scaled linear-domain forward: lane owns a 16-step chunk, builds the 3x3
// transfer-matrix product in linear space with exact power-of-2 renorm;
// 6-stage ordered shfl_xor butterfly composes 64 chunks per wave
// (1 wave = 1 sequence). Gold score fused.
// R8 = R7 resubmitted (round-4 bench died on container infra, not kernel).
// R7 theory: R3's body verbatim; the ONE variable is the register cap +
// load-burst pinning. R3 compiled to VGPR=60 -- the 20-float4 burst needs
// ~80 dest regs, so the compiler sank the loads into the body = 4-5
// dependent ~800cyc round trips/wave, block-synchronized stalls
// (VALUBusy 27%). R5 proved 3.5TB/s is deliverable with enough in-flight
// loads; R6 proved rolled loops shred cache-line locality (FETCH 82->248MB).
// Fix: launch_bounds(256,3) (cap ~170 VGPR, still 3 waves/SIMD), loads
// issued interleaved by consumption group, sched_barrier(0) pins them.

#define LOG2E 1.4426950408889634f
#define LN2   0.6931471805599453f

constexpr int B = 8192;
constexpr int L = 1024;
constexpr int SEQS_PER_BLOCK = 4;   // 4 waves of 64 per block

__device__ __forceinline__ float fexp2(float x) { return __builtin_amdgcn_exp2f(x); }
__device__ __forceinline__ float flog2(float x) { return __builtin_amdgcn_logf(x); }

__device__ __forceinline__ float f4get(const float4& v, int c) {
  return c == 0 ? v.x : (c == 1 ? v.y : (c == 2 ? v.z : v.w));
}
__device__ __forceinline__ int i4get(const int4& v, int c) {
  return c == 0 ? v.x : (c == 1 ? v.y : (c == 2 ? v.z : v.w));
}

__device__ __forceinline__ float mux3(float x0, float x1, float x2, int i) {
  return (i == 0) ? x0 : ((i == 1) ? x1 : x2);
}
// transitions[p][c] via cndmask chain (no dynamic register indexing)
__device__ __forceinline__ float trmux(const float* __restrict__ T2, int p, int c) {
  const float r0 = mux3(T2[0], T2[1], T2[2], c);
  const float r1 = mux3(T2[3], T2[4], T2[5], c);
  const float r2 = mux3(T2[6], T2[7], T2[8], c);
  return mux3(r0, r1, r2, p);
}

__device__ __forceinline__ void matmul3(float* __restrict__ D,
                                        const float* __restrict__ A,
                                        const float* __restrict__ Bm) {
  #pragma unroll
  for (int i = 0; i < 3; ++i)
    #pragma unroll
    for (int j = 0; j < 3; ++j)
      D[i * 3 + j] = A[i * 3 + 0] * Bm[0 * 3 + j] +
                     A[i * 3 + 1] * Bm[1 * 3 + j] +
                     A[i * 3 + 2] * Bm[2 * 3 + j];
}

// Exact power-of-2 renormalization: P *= 2^-ex, scale += ex.
__device__ __forceinline__ void renorm3(float* __restrict__ P, float& scale) {
  float m = P[0];
  #pragma unroll
  for (int e = 1; e < 9; ++e) m = fmaxf(m, P[e]);
  int ex;
  (void)frexpf(m, &ex);
  #pragma unroll
  for (int e = 0; e < 9; ++e) P[e] = ldexpf(P[e], -ex);
  scale += (float)ex;
}

__global__ __launch_bounds__(256, 3) void crf_main(
    const float* __restrict__ em, const float* __restrict__ mask,
    const float* __restrict__ trans, const int* __restrict__ tags,
    float* __restrict__ out) {
  const int lane = threadIdx.x & 63;
  const int wid = threadIdx.x >> 6;
  const int b = blockIdx.x * SEQS_PER_BLOCK + wid;

  const float4* em4 = (const float4*)(em + (size_t)b * (L * 3)) + lane * 12;
  const float4* mk4 = (const float4*)(mask + (size_t)b * L) + lane * 4;
  const int4*   tg4 = (const int4*)(tags + (size_t)b * L) + lane * 4;

  // ---- ALL global loads up front, interleaved by consumption group ----
  // (group g's first use waits only on its own 5 loads via partial vmcnt)
  float4 E[12];
  float4 MK[4];
  int4 TG[4];
  #pragma unroll
  for (int g = 0; g < 4; ++g) {
    E[3 * g + 0] = em4[3 * g + 0];
    E[3 * g + 1] = em4[3 * g + 1];
    E[3 * g + 2] = em4[3 * g + 2];
    MK[g] = mk4[g];
    TG[g] = tg4[g];
  }
  // Pin: nothing (esp. these loads) may be scheduled across this point.
  __builtin_amdgcn_sched_barrier(0);

  // Transitions: log2 domain + linear form (uniform -> scalar loads).
  // Computed while the burst is in flight.
  float T2[9], tk[9];
  #pragma unroll
  for (int e = 0; e < 9; ++e) {
    T2[e] = trans[e] * LOG2E;
    tk[e] = fexp2(T2[e]);
  }

  float P[9] = {1.f, 0.f, 0.f, 0.f, 1.f, 0.f, 0.f, 0.f, 1.f};
  float scale = 0.f, gold = 0.f;
  float a0 = 0.f, a1 = 0.f, a2 = 0.f;   // step-0 linear emissions (lane 0)
  float e0_sel = 0.f, mk0 = 0.f;        // deferred step-0 gold term
  int tag0 = 0, prev = 0;

  #pragma unroll
  for (int s = 0; s < 16; ++s) {
    const float ev0 = f4get(E[(3 * s + 0) >> 2], (3 * s + 0) & 3) * LOG2E;
    const float ev1 = f4get(E[(3 * s + 1) >> 2], (3 * s + 1) & 3) * LOG2E;
    const float ev2 = f4get(E[(3 * s + 2) >> 2], (3 * s + 2) & 3) * LOG2E;
    const float m   = f4get(MK[s >> 2], s & 3);
    const int   cur = i4get(TG[s >> 2], s & 3);

    // ---- gold score (log2 domain) ----
    const float e = mux3(ev0, ev1, ev2, cur);
    if (s == 0) {
      e0_sel = e; mk0 = m; tag0 = cur;   // cross-lane prev tag fixed up later
    } else {
      gold = fmaf(trmux(T2, prev, cur) + e, m, gold);
    }
    prev = cur;

    // ---- matrix step (linear domain): M = act ? tk.*w : I ----
    const float w0 = fexp2(ev0);
    const float w1 = fexp2(ev1);
    const float w2 = fexp2(ev2);
    if (s == 0) { a0 = w0; a1 = w1; a2 = w2; }
    const bool act = (m > 0.f) && !(s == 0 && lane == 0);  // t=0 is alpha0
    const float g  = act ? 1.f : 0.f;
    const float c1 = 1.f - g;
    const float u0 = w0 * g, u1 = w1 * g, u2 = w2 * g;
    float M[9];
    M[0] = fmaf(tk[0], u0, c1); M[1] = tk[1] * u1;           M[2] = tk[2] * u2;
    M[3] = tk[3] * u0;          M[4] = fmaf(tk[4], u1, c1);  M[5] = tk[5] * u2;
    M[6] = tk[6] * u0;          M[7] = tk[7] * u1;           M[8] = fmaf(tk[8], u2, c1);
    float N[9];
    matmul3(N, P, M);
    #pragma unroll
    for (int e2 = 0; e2 < 9; ++e2) P[e2] = N[e2];

    if (s == 7 || s == 15) renorm3(P, scale);  // bound fp32 range
  }

  // ---- deferred step-0 gold term (needs previous lane's last tag) ----
  const int prevLast = __shfl_up(prev, 1);
  if (lane == 0) gold = fmaf(e0_sel, mk0, gold);
  else           gold = fmaf(trmux(T2, prevLast, tag0) + e0_sel, mk0, gold);
  #pragma unroll
  for (int d = 1; d < 64; d <<= 1) gold += __shfl_xor(gold, d, 64);

  // ---- ordered butterfly combine (entries <= 3^6 = 729: no renorm needed) ----
  #pragma unroll
  for (int d = 1; d < 64; d <<= 1) {
    float o[9];
    #pragma unroll
    for (int e = 0; e < 9; ++e) o[e] = __shfl_xor(P[e], d, 64);
    const float osc = __shfl_xor(scale, d, 64);
    const bool later = (lane & d) != 0;  // self covers the later time segment
    float A[9], Bm[9];
    #pragma unroll
    for (int e = 0; e < 9; ++e) {
      A[e]  = later ? o[e] : P[e];
      Bm[e] = later ? P[e] : o[e];
    }
    float N[9];
    matmul3(N, A, Bm);
    #pragma unroll
    for (int e = 0; e < 9; ++e) P[e] = N[e];
    scale += osc;
  }

  // ---- finalize + block reduce + atomic ----
  __shared__ float red[SEQS_PER_BLOCK];
  if (lane == 0) {
    const float z = a0 * (P[0] + P[1] + P[2]) +
                    a1 * (P[3] + P[4] + P[5]) +
                    a2 * (P[6] + P[7] + P[8]);
    red[wid] = LN2 * (scale + flog2(z) - gold);
  }
  __syncthreads();
  if (threadIdx.x == 0) {
    const float s = red[0] + red[1] + red[2] + red[3];
    atomicAdd(out, s * (1.0f / (float)B));
  }
}

extern "C" void kernel_launch(void* const* d_in, const int* in_sizes, int n_in,
                              void* d_out, int out_size, void* d_ws, size_t ws_size,
                              hipStream_t stream) {
  const float* em    = (const float*)d_in[0];
  const float* mask  = (const float*)d_in[1];
  const float* trans = (const float*)d_in[2];
  const int*   tags  = (const int*)d_in[3];
  float* out = (float*)d_out;

  hipMemsetAsync(out, 0, sizeof(float), stream);  // atomic accumulator init
  crf_main<<<B / SEQS_PER_BLOCK, 256, 0, stream>>>(em, mask, trans, tags, out);
}